// Round 5
// baseline (1177.861 us; speedup 1.0000x reference)
//
#include <hip/hip_runtime.h>
#include <hip/hip_bf16.h>

typedef __attribute__((ext_vector_type(8))) short short8;   // 8 bf16 (4 VGPR) MFMA A/B frag
typedef __attribute__((ext_vector_type(4))) short short4v;  // 4 bf16 (8B)
typedef __attribute__((ext_vector_type(4))) float f32x4;    // MFMA C/D frag

#define D_IN 1280
#define D_OUT 1280
#define RANK 4
#define LORA_STRIDE 4
#define BM 128
#define BN 128
#define BK 64
#define NK (D_IN / BK)   // 20

// fp32 -> bf16 round-to-nearest-even, bit-cast to short for LDS storage
__device__ __forceinline__ short f2bs(float f) {
    __hip_bfloat16 h = __float2bfloat16(f);
    return __builtin_bit_cast(short, h);
}

// LDS layout: row-major [row][64 bf16], 16-B chunk index XORed with (row&7)
// to spread banks for both staging writes and b128 frag reads. (0 measured
// bank conflicts — do not touch.)
__device__ __forceinline__ int swz(int row, int k) {
    return row * BK + ((((k >> 3) ^ row) & 7) << 3) + (k & 7);
}

// ---------------------------------------------------------------------------
// Double-buffered pipeline (R4, 751us) + LoRA moved off the staging path:
//  - B staging is PURE W (load + cvt only): the W_eff = W + Wu@Wd fold that
//    cost ~160 VALU/thread/step (and was recomputed by all 32 m-tiles) is gone.
//  - down = x @ Wd^T rides the MFMA pipe: 8 extra MFMAs/step reusing af[mi];
//    Wd b-frags come straight from global (20 KB, L1-hot), rank duplicated
//    across cols via row = lr&3 so no garbage lanes.
//  - up-projection (rank 4) happens once in the epilogue: 4 shfls within the
//    16-lane group + 4 FMA/element against pre-scaled Wu columns.
// ---------------------------------------------------------------------------
__global__ __launch_bounds__(256, 2)
void lora_gemm_mfma(const float* __restrict__ x,      // [M][D_IN]
                    const int* __restrict__ lora_id,  // [G]
                    const float* __restrict__ W,      // [D_OUT][D_IN]
                    const float* __restrict__ Wd,     // [L][RANK][D_IN]
                    const float* __restrict__ Wu,     // [L][D_OUT][RANK]
                    float* __restrict__ out,          // [M][D_OUT]
                    int t_len, int ntiles_n) {
    __shared__ short sA[2][BM * BK];  // 32 KB
    __shared__ short sB[2][BN * BK];  // 32 KB

    const int tid = threadIdx.x;

    // T1: XCD-aware chunked remap (proven FETCH-halver). nwg = 5120 % 8 == 0.
    const int nwg = gridDim.x;
    const int cpx = nwg >> 3;
    const int bsw = (blockIdx.x & 7) * cpx + (blockIdx.x >> 3);
    const int ntile = bsw % ntiles_n;
    const int mtile = bsw / ntiles_n;
    const int gm = mtile * BM;
    const int gn = ntile * BN;

    const int chunk = gm / t_len;       // block-uniform (BM divides t_len)
    const int lid_raw = lora_id[chunk];
    const bool active = lid_raw >= 0;
    const int idx = active ? (lid_raw / LORA_STRIDE) : 0;
    const float lscale = active ? 1.0f : 0.0f;  // SCALE = 1.0

    // A staging map: row = tid>>1, 32 contiguous k at (tid&1)*32
    const int arow = tid >> 1;
    const int acol = (tid & 1) * 32;
    const float* xp = x + (long)(gm + arow) * D_IN + acol;

    // B staging map: k-group kg of 4, rows nr+16s, s=0..7 (pure W now)
    const int kg = tid & 15;
    const int nr = tid >> 4;
    const float* wp = W + (long)gn * D_IN + kg * 4;

    // MFMA wave layout: 2x2 waves, each 64x64 = 4x4 tiles of 16x16
    const int wave = tid >> 6;
    const int lane = tid & 63;
    const int wm = (wave & 1) * 64;
    const int wn = (wave >> 1) * 64;
    const int quad = lane >> 4;
    const int lr = lane & 15;

    // Wd row for this lane's down b-frag: rank = lr, duplicated via &3 so
    // cols 4-15 of the down accumulator are benign copies of ranks 0-3.
    const float* wdl = Wd + ((long)idx * RANK + (lr & 3)) * D_IN;

    // Wu columns for this wave's n-range, pre-scaled by active flag (epilogue)
    f32x4 uw[4];
    #pragma unroll
    for (int ni = 0; ni < 4; ++ni) {
        f32x4 t = *reinterpret_cast<const f32x4*>(
            Wu + ((long)idx * D_OUT + gn + wn + ni * 16 + lr) * RANK);
        #pragma unroll
        for (int j = 0; j < 4; ++j) uw[ni][j] = t[j] * lscale;
    }

    f32x4 acc[4][4];
    f32x4 acc_d[4];   // down accumulator: rank in cols, rows = m
    #pragma unroll
    for (int a = 0; a < 4; ++a) {
        #pragma unroll
        for (int j = 0; j < 4; ++j) acc_d[a][j] = 0.f;
        #pragma unroll
        for (int b = 0; b < 4; ++b)
            #pragma unroll
            for (int j = 0; j < 4; ++j) acc[a][b][j] = 0.f;
    }

    // Staging registers — live across the MFMA phase in steady state.
    f32x4 xv[8], wv[8];

    // ---- prologue: load + stage K-step 0 into buffer 0 ----
    #pragma unroll
    for (int q = 0; q < 8; ++q)
        xv[q] = *reinterpret_cast<const f32x4*>(xp + q * 4);
    #pragma unroll
    for (int s = 0; s < 8; ++s)
        wv[s] = *reinterpret_cast<const f32x4*>(wp + (long)(nr + 16 * s) * D_IN);

    #pragma unroll
    for (int q = 0; q < 4; ++q) {
        short8 v;
        #pragma unroll
        for (int j = 0; j < 4; ++j) {
            v[j]     = f2bs(xv[2 * q][j]);
            v[j + 4] = f2bs(xv[2 * q + 1][j]);
        }
        *reinterpret_cast<short8*>(&sA[0][swz(arow, acol + q * 8)]) = v;
    }
    #pragma unroll
    for (int s = 0; s < 8; ++s) {
        short4v e;
        #pragma unroll
        for (int j = 0; j < 4; ++j) e[j] = f2bs(wv[s][j]);
        *reinterpret_cast<short4v*>(&sB[0][swz(nr + 16 * s, kg * 4)]) = e;
    }

    int cur = 0;
    for (int kt = 0; kt < NK; ++kt) {
        __syncthreads();  // buf[cur] visible; buf[cur^1] safe to overwrite

        // ---- issue loads for K-step kt+1 (latency hides under MFMA phase) ----
        const bool more = (kt + 1) < NK;
        if (more) {
            const int kn = (kt + 1) * BK;
            #pragma unroll
            for (int q = 0; q < 8; ++q)
                xv[q] = *reinterpret_cast<const f32x4*>(xp + kn + q * 4);
            #pragma unroll
            for (int s = 0; s < 8; ++s)
                wv[s] = *reinterpret_cast<const f32x4*>(
                    wp + (long)(nr + 16 * s) * D_IN + kn);
        }

        // ---- MFMA phase from buf[cur]: 2 k-steps of 32 ----
        const short* cA = sA[cur];
        const short* cB = sB[cur];
        #pragma unroll
        for (int ks = 0; ks < 2; ++ks) {
            // down b-frag source (L1-hot 20 KB table) — issue early so the
            // latency hides under the 16 base MFMAs.
            f32x4 d0 = *reinterpret_cast<const f32x4*>(
                wdl + kt * BK + ks * 32 + quad * 8);
            f32x4 d1 = *reinterpret_cast<const f32x4*>(
                wdl + kt * BK + ks * 32 + quad * 8 + 4);

            short8 af[4], bfr[4];
            #pragma unroll
            for (int mi = 0; mi < 4; ++mi)
                af[mi] = *reinterpret_cast<const short8*>(
                    &cA[swz(wm + mi * 16 + lr, ks * 32 + quad * 8)]);
            #pragma unroll
            for (int ni = 0; ni < 4; ++ni)
                bfr[ni] = *reinterpret_cast<const short8*>(
                    &cB[swz(wn + ni * 16 + lr, ks * 32 + quad * 8)]);

            #pragma unroll
            for (int mi = 0; mi < 4; ++mi)
                #pragma unroll
                for (int ni = 0; ni < 4; ++ni)
                    acc[mi][ni] = __builtin_amdgcn_mfma_f32_16x16x32_bf16(
                        af[mi], bfr[ni], acc[mi][ni], 0, 0, 0);

            short8 df;
            #pragma unroll
            for (int j = 0; j < 4; ++j) {
                df[j]     = f2bs(d0[j]);
                df[j + 4] = f2bs(d1[j]);
            }
            #pragma unroll
            for (int mi = 0; mi < 4; ++mi)
                acc_d[mi] = __builtin_amdgcn_mfma_f32_16x16x32_bf16(
                    af[mi], df, acc_d[mi], 0, 0, 0);
        }

        // ---- stage K-step kt+1 into buf[cur^1] (vmcnt waits land here) ----
        if (more) {
            short* nA = sA[cur ^ 1];
            short* nB = sB[cur ^ 1];
            #pragma unroll
            for (int q = 0; q < 4; ++q) {
                short8 v;
                #pragma unroll
                for (int j = 0; j < 4; ++j) {
                    v[j]     = f2bs(xv[2 * q][j]);
                    v[j + 4] = f2bs(xv[2 * q + 1][j]);
                }
                *reinterpret_cast<short8*>(&nA[swz(arow, acol + q * 8)]) = v;
            }
            #pragma unroll
            for (int s = 0; s < 8; ++s) {
                short4v e;
                #pragma unroll
                for (int j = 0; j < 4; ++j) e[j] = f2bs(wv[s][j]);
                *reinterpret_cast<short4v*>(&nB[swz(nr + 16 * s, kg * 4)]) = e;
            }
        }
        cur ^= 1;
    }

    // ---- epilogue: up-projection + store ----
    // acc_d[mi][j] = down[row = wm+mi*16+quad*4+j][rank = lane&15 (&3 dup)].
    // Gather down[row][r] from lane quad*16+r (same 16-lane group), then
    // acc += down . (Wu * lscale). C/D layout col=lane&15, row=quad*4+reg.
    #pragma unroll
    for (int mi = 0; mi < 4; ++mi) {
        float dm[4][4];  // [rank][j] — all indices compile-time constant
        #pragma unroll
        for (int r = 0; r < 4; ++r)
            #pragma unroll
            for (int j = 0; j < 4; ++j)
                dm[r][j] = __shfl(acc_d[mi][j], (lane & 48) + r);
        #pragma unroll
        for (int ni = 0; ni < 4; ++ni) {
            float* op = out + (long)(gm + wm + mi * 16 + quad * 4) * D_OUT
                            + gn + wn + ni * 16 + lr;
            #pragma unroll
            for (int j = 0; j < 4; ++j) {
                float v = acc[mi][ni][j]
                        + dm[0][j] * uw[ni][0] + dm[1][j] * uw[ni][1]
                        + dm[2][j] * uw[ni][2] + dm[3][j] * uw[ni][3];
                op[(long)j * D_OUT] = v;
            }
        }
    }
}

// ---------------------------------------------------------------------------
// Fallback for non-dividing shapes: the round-0 verified fused kernel.
// ---------------------------------------------------------------------------
__global__ __launch_bounds__(256, 2)
void lora_fused_gemm_fb(const float* __restrict__ x,
                        const int* __restrict__ lora_id,
                        const float* __restrict__ W,
                        const float* __restrict__ Wd,
                        const float* __restrict__ Wu,
                        float* __restrict__ out,
                        int t_len, int ntiles_n) {
    __shared__ short sA[BM * BK];
    __shared__ short sB[BN * BK];

    const int tid = threadIdx.x;
    const int bx = blockIdx.x;
    const int ntile = bx % ntiles_n;
    const int mtile = bx / ntiles_n;
    const int gm = mtile * BM;
    const int gn = ntile * BN;

    const int chunk = gm / t_len;
    const int lid_raw = lora_id[chunk];
    const bool active = lid_raw >= 0;
    const int idx = active ? (lid_raw / LORA_STRIDE) : 0;
    const float lscale = active ? 1.0f : 0.0f;

    const int arow = tid >> 1;
    const int acol = (tid & 1) * 32;
    const float* xp = x + (long)(gm + arow) * D_IN + acol;

    const int kg = tid & 15;
    const int nr = tid >> 4;
    const float* wp = W + (long)gn * D_IN + kg * 4;
    const float* wdp = Wd + (long)idx * RANK * D_IN + kg * 4;

    f32x4 u[8];
    #pragma unroll
    for (int s = 0; s < 8; ++s) {
        f32x4 t = *reinterpret_cast<const f32x4*>(
            Wu + ((long)idx * D_OUT + gn + nr + 16 * s) * RANK);
        #pragma unroll
        for (int j = 0; j < 4; ++j) u[s][j] = t[j] * lscale;
    }

    const int wave = tid >> 6;
    const int lane = tid & 63;
    const int wm = (wave & 1) * 64;
    const int wn = (wave >> 1) * 64;
    const int quad = lane >> 4;
    const int lr = lane & 15;

    f32x4 acc[4][4];
    #pragma unroll
    for (int a = 0; a < 4; ++a)
        #pragma unroll
        for (int b = 0; b < 4; ++b)
            #pragma unroll
            for (int j = 0; j < 4; ++j) acc[a][b][j] = 0.f;

    for (int k0 = 0; k0 < D_IN; k0 += BK) {
        if (k0) __syncthreads();

        f32x4 xv[8];
        #pragma unroll
        for (int q = 0; q < 8; ++q)
            xv[q] = *reinterpret_cast<const f32x4*>(xp + k0 + q * 4);
        #pragma unroll
        for (int q = 0; q < 4; ++q) {
            short8 v;
            #pragma unroll
            for (int j = 0; j < 4; ++j) {
                v[j]     = f2bs(xv[2 * q][j]);
                v[j + 4] = f2bs(xv[2 * q + 1][j]);
            }
            *reinterpret_cast<short8*>(&sA[swz(arow, acol + q * 8)]) = v;
        }

        f32x4 wd[RANK];
        #pragma unroll
        for (int r = 0; r < RANK; ++r)
            wd[r] = *reinterpret_cast<const f32x4*>(wdp + (long)r * D_IN + k0);
        #pragma unroll
        for (int s = 0; s < 8; ++s) {
            const int n = nr + 16 * s;
            f32x4 wv = *reinterpret_cast<const f32x4*>(wp + (long)n * D_IN + k0);
            short4v e;
            #pragma unroll
            for (int j = 0; j < 4; ++j) {
                float v = wv[j] + u[s][0] * wd[0][j] + u[s][1] * wd[1][j]
                                + u[s][2] * wd[2][j] + u[s][3] * wd[3][j];
                e[j] = f2bs(v);
            }
            *reinterpret_cast<short4v*>(&sB[swz(n, kg * 4)]) = e;
        }

        __syncthreads();

        #pragma unroll
        for (int ks = 0; ks < 2; ++ks) {
            short8 af[4], bfr[4];
            #pragma unroll
            for (int mi = 0; mi < 4; ++mi)
                af[mi] = *reinterpret_cast<const short8*>(
                    &sA[swz(wm + mi * 16 + lr, ks * 32 + quad * 8)]);
            #pragma unroll
            for (int ni = 0; ni < 4; ++ni)
                bfr[ni] = *reinterpret_cast<const short8*>(
                    &sB[swz(wn + ni * 16 + lr, ks * 32 + quad * 8)]);
            #pragma unroll
            for (int mi = 0; mi < 4; ++mi)
                #pragma unroll
                for (int ni = 0; ni < 4; ++ni)
                    acc[mi][ni] = __builtin_amdgcn_mfma_f32_16x16x32_bf16(
                        af[mi], bfr[ni], acc[mi][ni], 0, 0, 0);
        }
    }

    #pragma unroll
    for (int mi = 0; mi < 4; ++mi) {
        #pragma unroll
        for (int ni = 0; ni < 4; ++ni) {
            float* op = out + (long)(gm + wm + mi * 16 + quad * 4) * D_OUT
                            + gn + wn + ni * 16 + lr;
            #pragma unroll
            for (int j = 0; j < 4; ++j) op[(long)j * D_OUT] = acc[mi][ni][j];
        }
    }
}

extern "C" void kernel_launch(void* const* d_in, const int* in_sizes, int n_in,
                              void* d_out, int out_size, void* d_ws, size_t ws_size,
                              hipStream_t stream) {
    const float* x   = (const float*)d_in[0];
    const int* lid   = (const int*)d_in[1];
    const float* W   = (const float*)d_in[2];
    const float* Wd  = (const float*)d_in[3];
    const float* Wu  = (const float*)d_in[4];
    float* out       = (float*)d_out;

    const int M = in_sizes[0] / D_IN;     // 65536
    const int G = in_sizes[1];            // 16
    const int t_len = M / G;              // 4096
    const int ntiles_n = D_OUT / BN;      // 10
    const int nblocks = (M / BM) * ntiles_n;  // 5120

    if (M % BM == 0 && t_len % BM == 0 && (nblocks & 7) == 0) {
        lora_gemm_mfma<<<nblocks, 256, 0, stream>>>(
            x, lid, W, Wd, Wu, out, t_len, ntiles_n);
    } else {
        lora_fused_gemm_fb<<<nblocks, 256, 0, stream>>>(
            x, lid, W, Wd, Wu, out, t_len, ntiles_n);
    }
}

// Round 6
// 1080.521 us; speedup vs baseline: 1.0901x; 1.0901x over previous
//
#include <hip/hip_runtime.h>
#include <hip/hip_bf16.h>

typedef __attribute__((ext_vector_type(8))) short short8;   // 8 bf16 (4 VGPR) MFMA A/B frag
typedef __attribute__((ext_vector_type(4))) short short4v;  // 4 bf16 (8B)
typedef __attribute__((ext_vector_type(4))) float f32x4;    // MFMA C/D frag

#define D_IN 1280
#define D_OUT 1280
#define RANK 4
#define LORA_STRIDE 4
#define BM 128
#define BN 128
#define BK 64
#define NK (D_IN / BK)   // 20

// fp32 -> bf16 round-to-nearest-even, bit-cast to short for LDS storage
__device__ __forceinline__ short f2bs(float f) {
    __hip_bfloat16 h = __float2bfloat16(f);
    return __builtin_bit_cast(short, h);
}

// LDS layout: row-major [row][64 bf16], 16-B chunk index XORed with (row&7)
// to spread banks for both staging writes and b128 frag reads. (0 measured
// bank conflicts — do not touch.)
__device__ __forceinline__ int swz(int row, int k) {
    return row * BK + ((((k >> 3) ^ row) & 7) << 3) + (k & 7);
}

// ---------------------------------------------------------------------------
// R4 double-buffered pipeline (751us) + LoRA on the MFMA pipe (R5 algebra),
// with Wd staged ONCE into LDS in fragment-read order:
//  - B staging is PURE W (load + cvt only) — the W_eff fold (~160 VALU/
//    thread/step, recomputed by 32 m-tiles) is gone.
//  - down = x @ Wd^T: 8 extra MFMAs/step reusing af[mi]; df comes from a
//    10 KB LDS table read as ONE ds_read_b128 per ks — no global loads in
//    the MFMA phase, so vmcnt waits stay in the staging phase (R5's
//    regression was d0/d1 global loads forcing a vmcnt(0)-equivalent drain
//    of the whole next-tile prefetch inside the MFMA phase).
//  - up-projection (rank 4) once in the epilogue: 4 shfls + 4 FMA/element
//    against pre-scaled Wu columns (numerically validated in R5).
// sD layout [ktks][quad][rank][8]: the 64-lane read touches 16 distinct 16B
// chunks covering each bank exactly twice (2-way = free, m136), 4-lane
// broadcast within a chunk.
// ---------------------------------------------------------------------------
__global__ __launch_bounds__(256, 2)
void lora_gemm_mfma2(const float* __restrict__ x,      // [M][D_IN]
                     const int* __restrict__ lora_id,  // [G]
                     const float* __restrict__ W,      // [D_OUT][D_IN]
                     const float* __restrict__ Wd,     // [L][RANK][D_IN]
                     const float* __restrict__ Wu,     // [L][D_OUT][RANK]
                     float* __restrict__ out,          // [M][D_OUT]
                     int t_len, int ntiles_n) {
    __shared__ short sA[2][BM * BK];      // 32 KB
    __shared__ short sB[2][BN * BK];      // 32 KB
    __shared__ short sD[RANK * D_IN];     // 10 KB, [ktks][quad][rank][8]

    const int tid = threadIdx.x;

    // T1: XCD-aware chunked remap (proven FETCH-halver). nwg = 5120 % 8 == 0.
    const int nwg = gridDim.x;
    const int cpx = nwg >> 3;
    const int bsw = (blockIdx.x & 7) * cpx + (blockIdx.x >> 3);
    const int ntile = bsw % ntiles_n;
    const int mtile = bsw / ntiles_n;
    const int gm = mtile * BM;
    const int gn = ntile * BN;

    const int chunk = gm / t_len;       // block-uniform (BM divides t_len)
    const int lid_raw = lora_id[chunk];
    const bool active = lid_raw >= 0;
    const int idx = active ? (lid_raw / LORA_STRIDE) : 0;
    const float lscale = active ? 1.0f : 0.0f;  // SCALE = 1.0

    // A staging map: row = tid>>1, 32 contiguous k at (tid&1)*32
    const int arow = tid >> 1;
    const int acol = (tid & 1) * 32;
    const float* xp = x + (long)(gm + arow) * D_IN + acol;

    // B staging map: k-group kg of 4, rows nr+16s, s=0..7 (pure W)
    const int kg = tid & 15;
    const int nr = tid >> 4;
    const float* wp = W + (long)gn * D_IN + kg * 4;

    // MFMA wave layout: 2x2 waves, each 64x64 = 4x4 tiles of 16x16
    const int wave = tid >> 6;
    const int lane = tid & 63;
    const int wm = (wave & 1) * 64;
    const int wn = (wave >> 1) * 64;
    const int quad = lane >> 4;
    const int lr = lane & 15;

    // df read base: rank = lr&3 (dup x4 across cols), this lane's quad
    const int dbase = quad * 32 + (lr & 3) * 8;

    // Wu columns for this wave's n-range, pre-scaled by active flag (epilogue)
    f32x4 uw[4];
    #pragma unroll
    for (int ni = 0; ni < 4; ++ni) {
        f32x4 t = *reinterpret_cast<const f32x4*>(
            Wu + ((long)idx * D_OUT + gn + wn + ni * 16 + lr) * RANK);
        #pragma unroll
        for (int j = 0; j < 4; ++j) uw[ni][j] = t[j] * lscale;
    }

    f32x4 acc[4][4];
    f32x4 acc_d[4];   // down accumulator: rank in cols (dup), rows = m
    #pragma unroll
    for (int a = 0; a < 4; ++a) {
        #pragma unroll
        for (int j = 0; j < 4; ++j) acc_d[a][j] = 0.f;
        #pragma unroll
        for (int b = 0; b < 4; ++b)
            #pragma unroll
            for (int j = 0; j < 4; ++j) acc[a][b][j] = 0.f;
    }

    // Staging registers — live across the MFMA phase in steady state.
    f32x4 xv[8], wv[8];

    // ---- prologue: issue K-step 0 loads, stage Wd table, stage buffer 0 ----
    #pragma unroll
    for (int q = 0; q < 8; ++q)
        xv[q] = *reinterpret_cast<const f32x4*>(xp + q * 4);
    #pragma unroll
    for (int s = 0; s < 8; ++s)
        wv[s] = *reinterpret_cast<const f32x4*>(wp + (long)(nr + 16 * s) * D_IN);

    // Wd -> sD in fragment order: global i = r*1280 + k (coalesced in i);
    // dest = ktks*128 + quad*32 + r*8 + j with ktks=k>>5, quad=(k>>3)&3, j=k&7.
    {
        const float* wdg = Wd + (long)idx * RANK * D_IN;
        #pragma unroll
        for (int ii = 0; ii < RANK * D_IN / 256; ++ii) {
            const int i = tid + ii * 256;
            const int r = i / D_IN;
            const int k = i - r * D_IN;
            sD[((k >> 5) << 7) + (((k >> 3) & 3) << 5) + (r << 3) + (k & 7)]
                = f2bs(wdg[i]);
        }
    }

    #pragma unroll
    for (int q = 0; q < 4; ++q) {
        short8 v;
        #pragma unroll
        for (int j = 0; j < 4; ++j) {
            v[j]     = f2bs(xv[2 * q][j]);
            v[j + 4] = f2bs(xv[2 * q + 1][j]);
        }
        *reinterpret_cast<short8*>(&sA[0][swz(arow, acol + q * 8)]) = v;
    }
    #pragma unroll
    for (int s = 0; s < 8; ++s) {
        short4v e;
        #pragma unroll
        for (int j = 0; j < 4; ++j) e[j] = f2bs(wv[s][j]);
        *reinterpret_cast<short4v*>(&sB[0][swz(nr + 16 * s, kg * 4)]) = e;
    }

    int cur = 0;
    for (int kt = 0; kt < NK; ++kt) {
        __syncthreads();  // buf[cur] + sD visible; buf[cur^1] safe to overwrite

        // ---- issue loads for K-step kt+1 (latency hides under MFMA phase) ----
        const bool more = (kt + 1) < NK;
        if (more) {
            const int kn = (kt + 1) * BK;
            #pragma unroll
            for (int q = 0; q < 8; ++q)
                xv[q] = *reinterpret_cast<const f32x4*>(xp + kn + q * 4);
            #pragma unroll
            for (int s = 0; s < 8; ++s)
                wv[s] = *reinterpret_cast<const f32x4*>(
                    wp + (long)(nr + 16 * s) * D_IN + kn);
        }

        // ---- MFMA phase from buf[cur]: 2 k-steps of 32 (pure LDS + MFMA) ----
        const short* cA = sA[cur];
        const short* cB = sB[cur];
        #pragma unroll
        for (int ks = 0; ks < 2; ++ks) {
            short8 af[4], bfr[4];
            #pragma unroll
            for (int mi = 0; mi < 4; ++mi)
                af[mi] = *reinterpret_cast<const short8*>(
                    &cA[swz(wm + mi * 16 + lr, ks * 32 + quad * 8)]);
            #pragma unroll
            for (int ni = 0; ni < 4; ++ni)
                bfr[ni] = *reinterpret_cast<const short8*>(
                    &cB[swz(wn + ni * 16 + lr, ks * 32 + quad * 8)]);
            short8 df = *reinterpret_cast<const short8*>(
                &sD[(kt * 2 + ks) * 128 + dbase]);

            #pragma unroll
            for (int mi = 0; mi < 4; ++mi)
                #pragma unroll
                for (int ni = 0; ni < 4; ++ni)
                    acc[mi][ni] = __builtin_amdgcn_mfma_f32_16x16x32_bf16(
                        af[mi], bfr[ni], acc[mi][ni], 0, 0, 0);
            #pragma unroll
            for (int mi = 0; mi < 4; ++mi)
                acc_d[mi] = __builtin_amdgcn_mfma_f32_16x16x32_bf16(
                    af[mi], df, acc_d[mi], 0, 0, 0);
        }

        // ---- stage K-step kt+1 into buf[cur^1] (vmcnt waits land here) ----
        if (more) {
            short* nA = sA[cur ^ 1];
            short* nB = sB[cur ^ 1];
            #pragma unroll
            for (int q = 0; q < 4; ++q) {
                short8 v;
                #pragma unroll
                for (int j = 0; j < 4; ++j) {
                    v[j]     = f2bs(xv[2 * q][j]);
                    v[j + 4] = f2bs(xv[2 * q + 1][j]);
                }
                *reinterpret_cast<short8*>(&nA[swz(arow, acol + q * 8)]) = v;
            }
            #pragma unroll
            for (int s = 0; s < 8; ++s) {
                short4v e;
                #pragma unroll
                for (int j = 0; j < 4; ++j) e[j] = f2bs(wv[s][j]);
                *reinterpret_cast<short4v*>(&nB[swz(nr + 16 * s, kg * 4)]) = e;
            }
        }
        cur ^= 1;
    }

    // ---- epilogue: up-projection + store (R5-validated) ----
    // acc_d[mi][j] = down[row = wm+mi*16+quad*4+j][rank = lr&3].
    // Gather rank r from lane quad*16+r, then acc += down . (Wu * lscale).
    #pragma unroll
    for (int mi = 0; mi < 4; ++mi) {
        float dm[4][4];  // [rank][j] — compile-time indices only
        #pragma unroll
        for (int r = 0; r < 4; ++r)
            #pragma unroll
            for (int j = 0; j < 4; ++j)
                dm[r][j] = __shfl(acc_d[mi][j], (lane & 48) + r);
        #pragma unroll
        for (int ni = 0; ni < 4; ++ni) {
            float* op = out + (long)(gm + wm + mi * 16 + quad * 4) * D_OUT
                            + gn + wn + ni * 16 + lr;
            #pragma unroll
            for (int j = 0; j < 4; ++j) {
                float v = acc[mi][ni][j]
                        + dm[0][j] * uw[ni][0] + dm[1][j] * uw[ni][1]
                        + dm[2][j] * uw[ni][2] + dm[3][j] * uw[ni][3];
                op[(long)j * D_OUT] = v;
            }
        }
    }
}

// ---------------------------------------------------------------------------
// Fallback for non-dividing shapes: the round-0 verified fused kernel.
// ---------------------------------------------------------------------------
__global__ __launch_bounds__(256, 2)
void lora_fused_gemm_fb(const float* __restrict__ x,
                        const int* __restrict__ lora_id,
                        const float* __restrict__ W,
                        const float* __restrict__ Wd,
                        const float* __restrict__ Wu,
                        float* __restrict__ out,
                        int t_len, int ntiles_n) {
    __shared__ short sA[BM * BK];
    __shared__ short sB[BN * BK];

    const int tid = threadIdx.x;
    const int bx = blockIdx.x;
    const int ntile = bx % ntiles_n;
    const int mtile = bx / ntiles_n;
    const int gm = mtile * BM;
    const int gn = ntile * BN;

    const int chunk = gm / t_len;
    const int lid_raw = lora_id[chunk];
    const bool active = lid_raw >= 0;
    const int idx = active ? (lid_raw / LORA_STRIDE) : 0;
    const float lscale = active ? 1.0f : 0.0f;

    const int arow = tid >> 1;
    const int acol = (tid & 1) * 32;
    const float* xp = x + (long)(gm + arow) * D_IN + acol;

    const int kg = tid & 15;
    const int nr = tid >> 4;
    const float* wp = W + (long)gn * D_IN + kg * 4;
    const float* wdp = Wd + (long)idx * RANK * D_IN + kg * 4;

    f32x4 u[8];
    #pragma unroll
    for (int s = 0; s < 8; ++s) {
        f32x4 t = *reinterpret_cast<const f32x4*>(
            Wu + ((long)idx * D_OUT + gn + nr + 16 * s) * RANK);
        #pragma unroll
        for (int j = 0; j < 4; ++j) u[s][j] = t[j] * lscale;
    }

    const int wave = tid >> 6;
    const int lane = tid & 63;
    const int wm = (wave & 1) * 64;
    const int wn = (wave >> 1) * 64;
    const int quad = lane >> 4;
    const int lr = lane & 15;

    f32x4 acc[4][4];
    #pragma unroll
    for (int a = 0; a < 4; ++a)
        #pragma unroll
        for (int b = 0; b < 4; ++b)
            #pragma unroll
            for (int j = 0; j < 4; ++j) acc[a][b][j] = 0.f;

    for (int k0 = 0; k0 < D_IN; k0 += BK) {
        if (k0) __syncthreads();

        f32x4 xv[8];
        #pragma unroll
        for (int q = 0; q < 8; ++q)
            xv[q] = *reinterpret_cast<const f32x4*>(xp + k0 + q * 4);
        #pragma unroll
        for (int q = 0; q < 4; ++q) {
            short8 v;
            #pragma unroll
            for (int j = 0; j < 4; ++j) {
                v[j]     = f2bs(xv[2 * q][j]);
                v[j + 4] = f2bs(xv[2 * q + 1][j]);
            }
            *reinterpret_cast<short8*>(&sA[swz(arow, acol + q * 8)]) = v;
        }

        f32x4 wd[RANK];
        #pragma unroll
        for (int r = 0; r < RANK; ++r)
            wd[r] = *reinterpret_cast<const f32x4*>(wdp + (long)r * D_IN + k0);
        #pragma unroll
        for (int s = 0; s < 8; ++s) {
            const int n = nr + 16 * s;
            f32x4 wv = *reinterpret_cast<const f32x4*>(wp + (long)n * D_IN + k0);
            short4v e;
            #pragma unroll
            for (int j = 0; j < 4; ++j) {
                float v = wv[j] + u[s][0] * wd[0][j] + u[s][1] * wd[1][j]
                                + u[s][2] * wd[2][j] + u[s][3] * wd[3][j];
                e[j] = f2bs(v);
            }
            *reinterpret_cast<short4v*>(&sB[swz(n, kg * 4)]) = e;
        }

        __syncthreads();

        #pragma unroll
        for (int ks = 0; ks < 2; ++ks) {
            short8 af[4], bfr[4];
            #pragma unroll
            for (int mi = 0; mi < 4; ++mi)
                af[mi] = *reinterpret_cast<const short8*>(
                    &sA[swz(wm + mi * 16 + lr, ks * 32 + quad * 8)]);
            #pragma unroll
            for (int ni = 0; ni < 4; ++ni)
                bfr[ni] = *reinterpret_cast<const short8*>(
                    &sB[swz(wn + ni * 16 + lr, ks * 32 + quad * 8)]);
            #pragma unroll
            for (int mi = 0; mi < 4; ++mi)
                #pragma unroll
                for (int ni = 0; ni < 4; ++ni)
                    acc[mi][ni] = __builtin_amdgcn_mfma_f32_16x16x32_bf16(
                        af[mi], bfr[ni], acc[mi][ni], 0, 0, 0);
        }
    }

    #pragma unroll
    for (int mi = 0; mi < 4; ++mi) {
        #pragma unroll
        for (int ni = 0; ni < 4; ++ni) {
            float* op = out + (long)(gm + wm + mi * 16 + quad * 4) * D_OUT
                            + gn + wn + ni * 16 + lr;
            #pragma unroll
            for (int j = 0; j < 4; ++j) op[(long)j * D_OUT] = acc[mi][ni][j];
        }
    }
}

extern "C" void kernel_launch(void* const* d_in, const int* in_sizes, int n_in,
                              void* d_out, int out_size, void* d_ws, size_t ws_size,
                              hipStream_t stream) {
    const float* x   = (const float*)d_in[0];
    const int* lid   = (const int*)d_in[1];
    const float* W   = (const float*)d_in[2];
    const float* Wd  = (const float*)d_in[3];
    const float* Wu  = (const float*)d_in[4];
    float* out       = (float*)d_out;

    const int M = in_sizes[0] / D_IN;     // 65536
    const int G = in_sizes[1];            // 16
    const int t_len = M / G;              // 4096
    const int ntiles_n = D_OUT / BN;      // 10
    const int nblocks = (M / BM) * ntiles_n;  // 5120

    if (M % BM == 0 && t_len % BM == 0 && (nblocks & 7) == 0) {
        lora_gemm_mfma2<<<nblocks, 256, 0, stream>>>(
            x, lid, W, Wd, Wu, out, t_len, ntiles_n);
    } else {
        lora_fused_gemm_fb<<<nblocks, 256, 0, stream>>>(
            x, lid, W, Wd, Wu, out, t_len, ntiles_n);
    }
}